// Round 3
// baseline (235.193 us; speedup 1.0000x reference)
//
#include <hip/hip_runtime.h>
#include <stdint.h>

#define B_SZ 8192
#define N_SZ 256
#define H_SZ 2048
#define LOG2PI_F 1.8378770664093453f
#define BETA_F 0.99f

typedef unsigned short ushort_t;
typedef __attribute__((ext_vector_type(8))) __bf16 bf16x8;
typedef __attribute__((ext_vector_type(4))) float f32x4;

__device__ __forceinline__ ushort_t f2bf(float f) {
    unsigned int u = __float_as_uint(f);
    unsigned int r = (u + 0x7FFFu + ((u >> 16) & 1u)) >> 16;  // RNE
    return (ushort_t)r;
}

__device__ __forceinline__ void async_ld16(const void* g, const char* lds_uniform) {
    __builtin_amdgcn_global_load_lds(
        (const __attribute__((address_space(1))) void*)g,
        (__attribute__((address_space(3))) void*)lds_uniform,
        16, 0, 0);
}

// 128x128 tile, BK=32. A[M,K] bf16 row-major, Bp[K/8,N,8] bf16 k-permuted.
// LDS: sA[kq][row][8] (conflict-free frag reads), sB[kq][col][8].
__device__ __forceinline__ void gemm_core(
    const ushort_t* __restrict__ A, const ushort_t* __restrict__ Bp,
    int N, int K, int k0base, int klen, int row0, int n0,
    char* sA, char* sB, f32x4 acc[4][4],
    int tid, int wbase, int q, int rlo, int wr, int wc)
{
    for (int k0 = k0base; k0 < k0base + klen; k0 += 32) {
        __syncthreads();  // previous compute done before LDS overwrite
#pragma unroll
        for (int r = 0; r < 2; ++r) {
            int c = r * 256 + tid;
            int mm = c & 127, kc = c >> 7;
            const ushort_t* gp = A + (size_t)(row0 + mm) * K + k0 + kc * 8;
            async_ld16(gp, sA + ((r * 256 + wbase) << 4));
        }
        int ko0 = k0 >> 3;
#pragma unroll
        for (int r = 0; r < 2; ++r) {
            int c = r * 256 + tid;
            int qq = c >> 7, nn = c & 127;
            const ushort_t* gp = Bp + ((size_t)(ko0 + qq) * N + n0 + nn) * 8;
            async_ld16(gp, sB + ((r * 256 + wbase) << 4));
        }
        __syncthreads();  // vmcnt drained before barrier: LDS ready

        bf16x8 af[4], bfr[4];
#pragma unroll
        for (int i = 0; i < 4; ++i) {
            int row = wr * 64 + i * 16 + rlo;
            af[i] = *(const bf16x8*)(sA + (((q << 7) + row) << 4));
        }
#pragma unroll
        for (int j = 0; j < 4; ++j) {
            int col = wc * 64 + j * 16 + rlo;
            bfr[j] = *(const bf16x8*)(sB + (((q << 7) + col) << 4));
        }
#pragma unroll
        for (int i = 0; i < 4; ++i)
#pragma unroll
            for (int j = 0; j < 4; ++j)
                acc[i][j] = __builtin_amdgcn_mfma_f32_16x16x32_bf16(af[i], bfr[j], acc[i][j], 0, 0, 0);
    }
}

// GEMM1 (tanh -> h) fused with Vx (rowsumsq(x@Wv) -> vx). Both read xb, K=256.
__global__ __launch_bounds__(256)
void gemm1_vx_kernel(const ushort_t* __restrict__ xb, const ushort_t* __restrict__ W1p,
                     const ushort_t* __restrict__ Wvp, const float* __restrict__ b1,
                     ushort_t* __restrict__ h, float* __restrict__ vx)
{
    __shared__ __align__(16) char smem[16384];
    char* sA = smem;
    char* sB = smem + 8192;
    const int tid = threadIdx.x;
    const int lane = tid & 63;
    const int w = tid >> 6;
    const int wbase = w << 6;
    const int q = lane >> 4;
    const int rlo = lane & 15;
    const int wr = w >> 1, wc = w & 1;
    const int row0 = blockIdx.y * 128;

    f32x4 acc[4][4];
#pragma unroll
    for (int i = 0; i < 4; ++i)
#pragma unroll
        for (int j = 0; j < 4; ++j)
            acc[i][j] = f32x4{0.f, 0.f, 0.f, 0.f};

    if (blockIdx.x < 16) {
        int n0 = blockIdx.x * 128;
        gemm_core(xb, W1p, H_SZ, N_SZ, 0, N_SZ, row0, n0, sA, sB, acc,
                  tid, wbase, q, rlo, wr, wc);
#pragma unroll
        for (int j = 0; j < 4; ++j) {
            int col = n0 + wc * 64 + j * 16 + rlo;
            float bv = b1[col];
#pragma unroll
            for (int i = 0; i < 4; ++i) {
                int rowb = row0 + wr * 64 + i * 16 + q * 4;
#pragma unroll
                for (int rr = 0; rr < 4; ++rr)
                    h[(size_t)(rowb + rr) * H_SZ + col] = f2bf(tanhf(acc[i][j][rr] + bv));
            }
        }
    } else {
        int n0 = (blockIdx.x - 16) * 128;
        gemm_core(xb, Wvp, N_SZ, N_SZ, 0, N_SZ, row0, n0, sA, sB, acc,
                  tid, wbase, q, rlo, wr, wc);
#pragma unroll
        for (int i = 0; i < 4; ++i) {
#pragma unroll
            for (int rr = 0; rr < 4; ++rr) {
                float s = 0.f;
#pragma unroll
                for (int j = 0; j < 4; ++j) { float v = acc[i][j][rr]; s += v * v; }
#pragma unroll
                for (int m = 1; m < 16; m <<= 1) s += __shfl_xor(s, m, 64);
                if (rlo == 0)
                    atomicAdd(&vx[row0 + wr * 64 + i * 16 + q * 4 + rr], s);
            }
        }
    }
}

// GEMM2 split-K: f += h@W2 chunk (f32 atomics, no bias). grid (4, 64, SPLITK)
#define SPLITK 4
__global__ __launch_bounds__(256)
void gemm2_kernel(const ushort_t* __restrict__ h, const ushort_t* __restrict__ W2p,
                  float* __restrict__ f)
{
    __shared__ __align__(16) char smem[16384];
    char* sA = smem;
    char* sB = smem + 8192;
    const int tid = threadIdx.x;
    const int lane = tid & 63;
    const int w = tid >> 6;
    const int wbase = w << 6;
    const int q = lane >> 4;
    const int rlo = lane & 15;
    const int wr = w >> 1, wc = w & 1;
    const int row0 = blockIdx.y * 128;
    const int n0 = blockIdx.x * 128;
    const int klen = H_SZ / SPLITK;
    const int k0base = blockIdx.z * klen;

    f32x4 acc[4][4];
#pragma unroll
    for (int i = 0; i < 4; ++i)
#pragma unroll
        for (int j = 0; j < 4; ++j)
            acc[i][j] = f32x4{0.f, 0.f, 0.f, 0.f};

    gemm_core(h, W2p, 512, H_SZ, k0base, klen, row0, n0, sA, sB, acc,
              tid, wbase, q, rlo, wr, wc);

#pragma unroll
    for (int j = 0; j < 4; ++j) {
        int col = n0 + wc * 64 + j * 16 + rlo;
#pragma unroll
        for (int i = 0; i < 4; ++i) {
            int rowb = row0 + wr * 64 + i * 16 + q * 4;
#pragma unroll
            for (int rr = 0; rr < 4; ++rr)
                unsafeAtomicAdd(&f[(size_t)(rowb + rr) * 512 + col], acc[i][j][rr]);
        }
    }
}

// Vmu = rowsumsq(mu@Wv). grid (2, 64)
__global__ __launch_bounds__(256)
void gemmv_kernel(const ushort_t* __restrict__ mub, const ushort_t* __restrict__ Wvp,
                  float* __restrict__ vmu)
{
    __shared__ __align__(16) char smem[16384];
    char* sA = smem;
    char* sB = smem + 8192;
    const int tid = threadIdx.x;
    const int lane = tid & 63;
    const int w = tid >> 6;
    const int wbase = w << 6;
    const int q = lane >> 4;
    const int rlo = lane & 15;
    const int wr = w >> 1, wc = w & 1;
    const int row0 = blockIdx.y * 128;
    const int n0 = blockIdx.x * 128;

    f32x4 acc[4][4];
#pragma unroll
    for (int i = 0; i < 4; ++i)
#pragma unroll
        for (int j = 0; j < 4; ++j)
            acc[i][j] = f32x4{0.f, 0.f, 0.f, 0.f};

    gemm_core(mub, Wvp, N_SZ, N_SZ, 0, N_SZ, row0, n0, sA, sB, acc,
              tid, wbase, q, rlo, wr, wc);

#pragma unroll
    for (int i = 0; i < 4; ++i) {
#pragma unroll
        for (int rr = 0; rr < 4; ++rr) {
            float s = 0.f;
#pragma unroll
            for (int j = 0; j < 4; ++j) { float v = acc[i][j][rr]; s += v * v; }
#pragma unroll
            for (int m = 1; m < 16; m <<= 1) s += __shfl_xor(s, m, 64);
            if (rlo == 0)
                atomicAdd(&vmu[row0 + wr * 64 + i * 16 + q * 4 + rr], s);
        }
    }
}

// f32 -> bf16 conversion + weight permutation to [K/8][N][8]; read-coalesced.
__global__ __launch_bounds__(256)
void convert_kernel(const float* __restrict__ x, const float* __restrict__ W1,
                    const float* __restrict__ W2, const float* __restrict__ Wv,
                    ushort_t* __restrict__ xb, ushort_t* __restrict__ W1p,
                    ushort_t* __restrict__ W2p, ushort_t* __restrict__ Wvp)
{
    const int XB = B_SZ * N_SZ;       // 2097152
    const int W1N = N_SZ * H_SZ;      // 524288
    const int W2N = H_SZ * 2 * N_SZ;  // 1048576
    const int WVN = N_SZ * N_SZ;      // 65536
    int idx = blockIdx.x * 256 + threadIdx.x;
    if (idx < XB) {
        xb[idx] = f2bf(x[idx]);
    } else if (idx < XB + W1N) {
        int d = idx - XB;
        int k = d >> 11, n = d & 2047;
        W1p[(size_t)(k >> 3) * (H_SZ * 8) + n * 8 + (k & 7)] = f2bf(W1[d]);
    } else if (idx < XB + W1N + W2N) {
        int d = idx - XB - W1N;
        int k = d >> 9, n = d & 511;
        W2p[(size_t)(k >> 3) * (512 * 8) + n * 8 + (k & 7)] = f2bf(W2[d]);
    } else if (idx < XB + W1N + W2N + WVN) {
        int d = idx - XB - W1N - W2N;
        int k = d >> 8, n = d & 255;
        Wvp[(size_t)(k >> 3) * (N_SZ * 8) + n * 8 + (k & 7)] = f2bf(Wv[d]);
    }
}

// mub = bf16(f[:, :256] + b2[:256])
__global__ __launch_bounds__(256)
void bias_mu_kernel(const float* __restrict__ f, const float* __restrict__ b2,
                    ushort_t* __restrict__ mub)
{
    int idx = blockIdx.x * 256 + threadIdx.x;
    int b = idx >> 8, n = idx & 255;
    mub[idx] = f2bf(f[(size_t)b * 512 + n] + b2[n]);
}

// per-row: scale ; fx ; logp row-sum -> partials[b]
__global__ __launch_bounds__(256)
void epilogue_kernel(const float* __restrict__ f, const float* __restrict__ b2,
                     const float* __restrict__ y, const float* __restrict__ eps,
                     const float* __restrict__ vx, const float* __restrict__ vmu,
                     float* __restrict__ out, float* __restrict__ partials)
{
    int b = blockIdx.x;
    int n = threadIdx.x;
    size_t bi = (size_t)b;
    float mu = f[bi * 512 + n] + b2[n];
    float lv = f[bi * 512 + 256 + n] + b2[256 + n];
    float var = expf(lv);
    float Vx = vx[b] + 1e-3f;
    float Vmu = vmu[b] + 1e-3f;
    float scale = fminf(BETA_F * Vx, Vmu) / Vmu;
    float mus = mu * scale;
    float e = eps[bi * 256 + n];
    float yy = y[bi * 256 + n];
    out[bi * 256 + n] = mus + sqrtf(var) * e;
    float d = yy - mus;
    float t = lv + d * d / var;
#pragma unroll
    for (int m = 32; m >= 1; m >>= 1) t += __shfl_down(t, m, 64);
    __shared__ float red[4];
    int lane = n & 63, wv = n >> 6;
    if (lane == 0) red[wv] = t;
    __syncthreads();
    if (n == 0)
        partials[b] = red[0] + red[1] + red[2] + red[3];
}

// single block: sum B_SZ partials, write scalar logp_y
__global__ __launch_bounds__(256)
void reduce_kernel(const float* __restrict__ partials, float* __restrict__ out)
{
    int tid = threadIdx.x;
    float s = 0.f;
#pragma unroll
    for (int i = 0; i < B_SZ / (256 * 4); ++i) {
        f32x4 v = *(const f32x4*)(partials + i * 1024 + tid * 4);
        s += v[0] + v[1] + v[2] + v[3];
    }
#pragma unroll
    for (int m = 32; m >= 1; m >>= 1) s += __shfl_down(s, m, 64);
    __shared__ float red[4];
    int lane = tid & 63, wv = tid >> 6;
    if (lane == 0) red[wv] = s;
    __syncthreads();
    if (tid == 0) {
        float tot = red[0] + red[1] + red[2] + red[3];
        out[(size_t)B_SZ * N_SZ] =
            0.5f * (tot + (float)N_SZ * LOG2PI_F * (float)B_SZ);
    }
}

extern "C" void kernel_launch(void* const* d_in, const int* in_sizes, int n_in,
                              void* d_out, int out_size, void* d_ws, size_t ws_size,
                              hipStream_t stream)
{
    const float* x   = (const float*)d_in[0];
    const float* y   = (const float*)d_in[1];
    const float* eps = (const float*)d_in[2];
    const float* W1  = (const float*)d_in[3];
    const float* b1  = (const float*)d_in[4];
    const float* W2  = (const float*)d_in[5];
    const float* b2  = (const float*)d_in[6];
    const float* Wv  = (const float*)d_in[7];
    float* out = (float*)d_out;

    char* ws = (char*)d_ws;
    size_t off = 0;
    auto alloc = [&](size_t bytes) {
        char* p = ws + off;
        off += (bytes + 255) & ~(size_t)255;
        return p;
    };
    ushort_t* xb  = (ushort_t*)alloc((size_t)B_SZ * N_SZ * 2);
    ushort_t* W1p = (ushort_t*)alloc((size_t)N_SZ * H_SZ * 2);
    ushort_t* W2p = (ushort_t*)alloc((size_t)H_SZ * 512 * 2);
    ushort_t* Wvp = (ushort_t*)alloc((size_t)N_SZ * N_SZ * 2);
    ushort_t* h   = (ushort_t*)alloc((size_t)B_SZ * H_SZ * 2);
    float*    f   = (float*)alloc((size_t)B_SZ * 512 * 4);
    ushort_t* mub = (ushort_t*)alloc((size_t)B_SZ * N_SZ * 2);
    float*    vx  = (float*)alloc((size_t)B_SZ * 4);
    float*    vmu = (float*)alloc((size_t)B_SZ * 4);
    float*    partials = (float*)alloc((size_t)B_SZ * 4);

    hipMemsetAsync(vx, 0, (size_t)B_SZ * 4, stream);
    hipMemsetAsync(vmu, 0, (size_t)B_SZ * 4, stream);
    hipMemsetAsync(f, 0, (size_t)B_SZ * 512 * 4, stream);

    const int TOTAL = B_SZ * N_SZ + N_SZ * H_SZ + H_SZ * 2 * N_SZ + N_SZ * N_SZ;
    convert_kernel<<<(TOTAL + 255) / 256, 256, 0, stream>>>(x, W1, W2, Wv, xb, W1p, W2p, Wvp);

    // h = tanh(x@W1 + b1)  (+ fused Vx = rowsumsq(x@Wv))
    gemm1_vx_kernel<<<dim3(18, B_SZ / 128), 256, 0, stream>>>(xb, W1p, Wvp, b1, h, vx);
    // f += h@W2 (split-K atomics, no bias)
    gemm2_kernel<<<dim3(4, B_SZ / 128, SPLITK), 256, 0, stream>>>(h, W2p, f);
    // mub = bf16(f[:, :256] + b2[:256])
    bias_mu_kernel<<<(B_SZ * N_SZ) / 256, 256, 0, stream>>>(f, b2, mub);
    // Vmu = rowsumsq(mu@Wv)
    gemmv_kernel<<<dim3(2, B_SZ / 128), 256, 0, stream>>>(mub, Wvp, vmu);

    epilogue_kernel<<<B_SZ, 256, 0, stream>>>(f, b2, y, eps, vx, vmu, out, partials);
    reduce_kernel<<<1, 256, 0, stream>>>(partials, out);
}

// Round 4
// 190.710 us; speedup vs baseline: 1.2332x; 1.2332x over previous
//
#include <hip/hip_runtime.h>
#include <stdint.h>

#define B_SZ 8192
#define N_SZ 256
#define H_SZ 2048
#define LOG2PI_F 1.8378770664093453f
#define BETA_F 0.99f

typedef unsigned short ushort_t;
typedef __attribute__((ext_vector_type(8))) __bf16 bf16x8;
typedef __attribute__((ext_vector_type(4))) float f32x4;

__device__ __forceinline__ ushort_t f2bf(float f) {
    unsigned int u = __float_as_uint(f);
    unsigned int r = (u + 0x7FFFu + ((u >> 16) & 1u)) >> 16;  // RNE
    return (ushort_t)r;
}

__device__ __forceinline__ void async_ld16(const void* g, const char* lds_uniform) {
    __builtin_amdgcn_global_load_lds(
        (const __attribute__((address_space(1))) void*)g,
        (__attribute__((address_space(3))) void*)lds_uniform,
        16, 0, 0);
}

// ---------------- 128x128 tile core (BK=32), used by gemm1_vx ----------------
// LDS: sA[kq][row128][8], sB[kq][col128][8] — conflict-free frag reads.
__device__ __forceinline__ void gemm_core128(
    const ushort_t* __restrict__ A, const ushort_t* __restrict__ Bp,
    int N, int K, int row0, int n0,
    char* sA, char* sB, f32x4 acc[4][4],
    int tid, int wbase, int q, int rlo, int wr, int wc)
{
    for (int k0 = 0; k0 < K; k0 += 32) {
        __syncthreads();
#pragma unroll
        for (int r = 0; r < 2; ++r) {
            int c = r * 256 + tid;
            int mm = c & 127, kc = c >> 7;
            const ushort_t* gp = A + (size_t)(row0 + mm) * K + k0 + kc * 8;
            async_ld16(gp, sA + ((r * 256 + wbase) << 4));
        }
        int ko0 = k0 >> 3;
#pragma unroll
        for (int r = 0; r < 2; ++r) {
            int c = r * 256 + tid;
            int qq = c >> 7, nn = c & 127;
            const ushort_t* gp = Bp + ((size_t)(ko0 + qq) * N + n0 + nn) * 8;
            async_ld16(gp, sB + ((r * 256 + wbase) << 4));
        }
        __syncthreads();

        bf16x8 af[4], bfr[4];
#pragma unroll
        for (int i = 0; i < 4; ++i) {
            int row = wr * 64 + i * 16 + rlo;
            af[i] = *(const bf16x8*)(sA + (((q << 7) + row) << 4));
        }
#pragma unroll
        for (int j = 0; j < 4; ++j) {
            int col = wc * 64 + j * 16 + rlo;
            bfr[j] = *(const bf16x8*)(sB + (((q << 7) + col) << 4));
        }
#pragma unroll
        for (int i = 0; i < 4; ++i)
#pragma unroll
            for (int j = 0; j < 4; ++j)
                acc[i][j] = __builtin_amdgcn_mfma_f32_16x16x32_bf16(af[i], bfr[j], acc[i][j], 0, 0, 0);
    }
}

// ---------------- 64x128 tile core (BK=32), used by gemm2 / gemmv -----------
// LDS: sA[kq][row64][8] (4 KB), sB[kq][col128][8] (8 KB).
__device__ __forceinline__ void gemm_core64(
    const ushort_t* __restrict__ A, const ushort_t* __restrict__ Bp,
    int N, int K, int row0, int n0,
    char* sA, char* sB, f32x4 acc[2][4],
    int tid, int wbase, int q, int rlo, int wr, int wc)
{
    for (int k0 = 0; k0 < K; k0 += 32) {
        __syncthreads();
        {   // A tile: 256 chunks x 16B, 1 per thread
            int mm = tid & 63, kc = tid >> 6;
            const ushort_t* gp = A + (size_t)(row0 + mm) * K + k0 + kc * 8;
            async_ld16(gp, sA + (wbase << 4));
        }
        int ko0 = k0 >> 3;
#pragma unroll
        for (int r = 0; r < 2; ++r) {
            int c = r * 256 + tid;
            int qq = c >> 7, nn = c & 127;
            const ushort_t* gp = Bp + ((size_t)(ko0 + qq) * N + n0 + nn) * 8;
            async_ld16(gp, sB + ((r * 256 + wbase) << 4));
        }
        __syncthreads();

        bf16x8 af[2], bfr[4];
#pragma unroll
        for (int i = 0; i < 2; ++i) {
            int row = wr * 32 + i * 16 + rlo;
            af[i] = *(const bf16x8*)(sA + (((q << 6) + row) << 4));
        }
#pragma unroll
        for (int j = 0; j < 4; ++j) {
            int col = wc * 64 + j * 16 + rlo;
            bfr[j] = *(const bf16x8*)(sB + (((q << 7) + col) << 4));
        }
#pragma unroll
        for (int i = 0; i < 2; ++i)
#pragma unroll
            for (int j = 0; j < 4; ++j)
                acc[i][j] = __builtin_amdgcn_mfma_f32_16x16x32_bf16(af[i], bfr[j], acc[i][j], 0, 0, 0);
    }
}

// GEMM1 (tanh -> h) fused with Vx (rowsumsq(x@Wv) -> vx). Both read xb, K=256.
__global__ __launch_bounds__(256)
void gemm1_vx_kernel(const ushort_t* __restrict__ xb, const ushort_t* __restrict__ W1p,
                     const ushort_t* __restrict__ Wvp, const float* __restrict__ b1,
                     ushort_t* __restrict__ h, float* __restrict__ vx)
{
    __shared__ __align__(16) char smem[16384];
    char* sA = smem;
    char* sB = smem + 8192;
    const int tid = threadIdx.x;
    const int lane = tid & 63;
    const int w = tid >> 6;
    const int wbase = w << 6;
    const int q = lane >> 4;
    const int rlo = lane & 15;
    const int wr = w >> 1, wc = w & 1;
    const int row0 = blockIdx.y * 128;

    f32x4 acc[4][4];
#pragma unroll
    for (int i = 0; i < 4; ++i)
#pragma unroll
        for (int j = 0; j < 4; ++j)
            acc[i][j] = f32x4{0.f, 0.f, 0.f, 0.f};

    if (blockIdx.x < 16) {
        int n0 = blockIdx.x * 128;
        gemm_core128(xb, W1p, H_SZ, N_SZ, row0, n0, sA, sB, acc,
                     tid, wbase, q, rlo, wr, wc);
#pragma unroll
        for (int j = 0; j < 4; ++j) {
            int col = n0 + wc * 64 + j * 16 + rlo;
            float bv = b1[col];
#pragma unroll
            for (int i = 0; i < 4; ++i) {
                int rowb = row0 + wr * 64 + i * 16 + q * 4;
#pragma unroll
                for (int rr = 0; rr < 4; ++rr)
                    h[(size_t)(rowb + rr) * H_SZ + col] = f2bf(tanhf(acc[i][j][rr] + bv));
            }
        }
    } else {
        int n0 = (blockIdx.x - 16) * 128;
        gemm_core128(xb, Wvp, N_SZ, N_SZ, row0, n0, sA, sB, acc,
                     tid, wbase, q, rlo, wr, wc);
#pragma unroll
        for (int i = 0; i < 4; ++i) {
#pragma unroll
            for (int rr = 0; rr < 4; ++rr) {
                float s = 0.f;
#pragma unroll
                for (int j = 0; j < 4; ++j) { float v = acc[i][j][rr]; s += v * v; }
#pragma unroll
                for (int m = 1; m < 16; m <<= 1) s += __shfl_xor(s, m, 64);
                if (rlo == 0)
                    atomicAdd(&vx[row0 + wr * 64 + i * 16 + q * 4 + rr], s);
            }
        }
    }
}

// GEMM2: f = h@W2 + b2 (f32) and mub = bf16(f[:, :256]). M64 tile, grid (4,128).
__global__ __launch_bounds__(256)
void gemm2_kernel(const ushort_t* __restrict__ h, const ushort_t* __restrict__ W2p,
                  const float* __restrict__ b2, float* __restrict__ f,
                  ushort_t* __restrict__ mub)
{
    __shared__ __align__(16) char smem[12288];
    char* sA = smem;          // 4 KB
    char* sB = smem + 4096;   // 8 KB
    const int tid = threadIdx.x;
    const int lane = tid & 63;
    const int w = tid >> 6;
    const int wbase = w << 6;
    const int q = lane >> 4;
    const int rlo = lane & 15;
    const int wr = w >> 1, wc = w & 1;
    const int row0 = blockIdx.y * 64;
    const int n0 = blockIdx.x * 128;

    f32x4 acc[2][4];
#pragma unroll
    for (int i = 0; i < 2; ++i)
#pragma unroll
        for (int j = 0; j < 4; ++j)
            acc[i][j] = f32x4{0.f, 0.f, 0.f, 0.f};

    gemm_core64(h, W2p, 512, H_SZ, row0, n0, sA, sB, acc,
                tid, wbase, q, rlo, wr, wc);

#pragma unroll
    for (int j = 0; j < 4; ++j) {
        int col = n0 + wc * 64 + j * 16 + rlo;
        float bv = b2[col];
#pragma unroll
        for (int i = 0; i < 2; ++i) {
            int rowb = row0 + wr * 32 + i * 16 + q * 4;
#pragma unroll
            for (int rr = 0; rr < 4; ++rr) {
                float v = acc[i][j][rr] + bv;
                f[(size_t)(rowb + rr) * 512 + col] = v;
                if (col < N_SZ)
                    mub[(size_t)(rowb + rr) * N_SZ + col] = f2bf(v);
            }
        }
    }
}

// Vmu = rowsumsq(mu@Wv). M64 tile, grid (2, 128).
__global__ __launch_bounds__(256)
void gemmv_kernel(const ushort_t* __restrict__ mub, const ushort_t* __restrict__ Wvp,
                  float* __restrict__ vmu)
{
    __shared__ __align__(16) char smem[12288];
    char* sA = smem;
    char* sB = smem + 4096;
    const int tid = threadIdx.x;
    const int lane = tid & 63;
    const int w = tid >> 6;
    const int wbase = w << 6;
    const int q = lane >> 4;
    const int rlo = lane & 15;
    const int wr = w >> 1, wc = w & 1;
    const int row0 = blockIdx.y * 64;
    const int n0 = blockIdx.x * 128;

    f32x4 acc[2][4];
#pragma unroll
    for (int i = 0; i < 2; ++i)
#pragma unroll
        for (int j = 0; j < 4; ++j)
            acc[i][j] = f32x4{0.f, 0.f, 0.f, 0.f};

    gemm_core64(mub, Wvp, N_SZ, N_SZ, row0, n0, sA, sB, acc,
                tid, wbase, q, rlo, wr, wc);

#pragma unroll
    for (int i = 0; i < 2; ++i) {
#pragma unroll
        for (int rr = 0; rr < 4; ++rr) {
            float s = 0.f;
#pragma unroll
            for (int j = 0; j < 4; ++j) { float v = acc[i][j][rr]; s += v * v; }
#pragma unroll
            for (int m = 1; m < 16; m <<= 1) s += __shfl_xor(s, m, 64);
            if (rlo == 0)
                atomicAdd(&vmu[row0 + wr * 32 + i * 16 + q * 4 + rr], s);
        }
    }
}

// f32 -> bf16 conversion + weight permutation to [K/8][N][8]; read-coalesced.
__global__ __launch_bounds__(256)
void convert_kernel(const float* __restrict__ x, const float* __restrict__ W1,
                    const float* __restrict__ W2, const float* __restrict__ Wv,
                    ushort_t* __restrict__ xb, ushort_t* __restrict__ W1p,
                    ushort_t* __restrict__ W2p, ushort_t* __restrict__ Wvp)
{
    const int XB = B_SZ * N_SZ;       // 2097152
    const int W1N = N_SZ * H_SZ;      // 524288
    const int W2N = H_SZ * 2 * N_SZ;  // 1048576
    const int WVN = N_SZ * N_SZ;      // 65536
    int idx = blockIdx.x * 256 + threadIdx.x;
    if (idx < XB) {
        xb[idx] = f2bf(x[idx]);
    } else if (idx < XB + W1N) {
        int d = idx - XB;
        int k = d >> 11, n = d & 2047;
        W1p[(size_t)(k >> 3) * (H_SZ * 8) + n * 8 + (k & 7)] = f2bf(W1[d]);
    } else if (idx < XB + W1N + W2N) {
        int d = idx - XB - W1N;
        int k = d >> 9, n = d & 511;
        W2p[(size_t)(k >> 3) * (512 * 8) + n * 8 + (k & 7)] = f2bf(W2[d]);
    } else if (idx < XB + W1N + W2N + WVN) {
        int d = idx - XB - W1N - W2N;
        int k = d >> 8, n = d & 255;
        Wvp[(size_t)(k >> 3) * (N_SZ * 8) + n * 8 + (k & 7)] = f2bf(Wv[d]);
    }
}

// per-row: scale ; fx ; logp row-sum -> partials[b]  (f already has bias)
__global__ __launch_bounds__(256)
void epilogue_kernel(const float* __restrict__ f, const float* __restrict__ y,
                     const float* __restrict__ eps, const float* __restrict__ vx,
                     const float* __restrict__ vmu, float* __restrict__ out,
                     float* __restrict__ partials)
{
    int b = blockIdx.x;
    int n = threadIdx.x;
    size_t bi = (size_t)b;
    float mu = f[bi * 512 + n];
    float lv = f[bi * 512 + 256 + n];
    float var = expf(lv);
    float Vx = vx[b] + 1e-3f;
    float Vmu = vmu[b] + 1e-3f;
    float scale = fminf(BETA_F * Vx, Vmu) / Vmu;
    float mus = mu * scale;
    float e = eps[bi * 256 + n];
    float yy = y[bi * 256 + n];
    out[bi * 256 + n] = mus + sqrtf(var) * e;
    float d = yy - mus;
    float t = lv + d * d / var;
#pragma unroll
    for (int m = 32; m >= 1; m >>= 1) t += __shfl_down(t, m, 64);
    __shared__ float red[4];
    int lane = n & 63, wv = n >> 6;
    if (lane == 0) red[wv] = t;
    __syncthreads();
    if (n == 0)
        partials[b] = red[0] + red[1] + red[2] + red[3];
}

// single block: sum B_SZ partials, write scalar logp_y
__global__ __launch_bounds__(256)
void reduce_kernel(const float* __restrict__ partials, float* __restrict__ out)
{
    int tid = threadIdx.x;
    float s = 0.f;
#pragma unroll
    for (int i = 0; i < B_SZ / (256 * 4); ++i) {
        f32x4 v = *(const f32x4*)(partials + i * 1024 + tid * 4);
        s += v[0] + v[1] + v[2] + v[3];
    }
#pragma unroll
    for (int m = 32; m >= 1; m >>= 1) s += __shfl_down(s, m, 64);
    __shared__ float red[4];
    int lane = tid & 63, wv = tid >> 6;
    if (lane == 0) red[wv] = s;
    __syncthreads();
    if (tid == 0) {
        float tot = red[0] + red[1] + red[2] + red[3];
        out[(size_t)B_SZ * N_SZ] =
            0.5f * (tot + (float)N_SZ * LOG2PI_F * (float)B_SZ);
    }
}

extern "C" void kernel_launch(void* const* d_in, const int* in_sizes, int n_in,
                              void* d_out, int out_size, void* d_ws, size_t ws_size,
                              hipStream_t stream)
{
    const float* x   = (const float*)d_in[0];
    const float* y   = (const float*)d_in[1];
    const float* eps = (const float*)d_in[2];
    const float* W1  = (const float*)d_in[3];
    const float* b1  = (const float*)d_in[4];
    const float* W2  = (const float*)d_in[5];
    const float* b2  = (const float*)d_in[6];
    const float* Wv  = (const float*)d_in[7];
    float* out = (float*)d_out;

    char* ws = (char*)d_ws;
    size_t off = 0;
    auto alloc = [&](size_t bytes) {
        char* p = ws + off;
        off += (bytes + 255) & ~(size_t)255;
        return p;
    };
    ushort_t* xb  = (ushort_t*)alloc((size_t)B_SZ * N_SZ * 2);
    ushort_t* W1p = (ushort_t*)alloc((size_t)N_SZ * H_SZ * 2);
    ushort_t* W2p = (ushort_t*)alloc((size_t)H_SZ * 512 * 2);
    ushort_t* Wvp = (ushort_t*)alloc((size_t)N_SZ * N_SZ * 2);
    ushort_t* h   = (ushort_t*)alloc((size_t)B_SZ * H_SZ * 2);
    float*    f   = (float*)alloc((size_t)B_SZ * 512 * 4);
    ushort_t* mub = (ushort_t*)alloc((size_t)B_SZ * N_SZ * 2);
    float*    vx  = (float*)alloc((size_t)B_SZ * 4);
    float*    vmu = (float*)alloc((size_t)B_SZ * 4);
    float*    partials = (float*)alloc((size_t)B_SZ * 4);

    hipMemsetAsync(vx, 0, (size_t)B_SZ * 4, stream);
    hipMemsetAsync(vmu, 0, (size_t)B_SZ * 4, stream);

    const int TOTAL = B_SZ * N_SZ + N_SZ * H_SZ + H_SZ * 2 * N_SZ + N_SZ * N_SZ;
    convert_kernel<<<(TOTAL + 255) / 256, 256, 0, stream>>>(x, W1, W2, Wv, xb, W1p, W2p, Wvp);

    // h = tanh(x@W1 + b1)  (+ fused Vx = rowsumsq(x@Wv))
    gemm1_vx_kernel<<<dim3(18, B_SZ / 128), 256, 0, stream>>>(xb, W1p, Wvp, b1, h, vx);
    // f = h@W2 + b2 ; mub = bf16(mu)
    gemm2_kernel<<<dim3(4, B_SZ / 64), 256, 0, stream>>>(h, W2p, b2, f, mub);
    // Vmu = rowsumsq(mu@Wv)
    gemmv_kernel<<<dim3(2, B_SZ / 64), 256, 0, stream>>>(mub, Wvp, vmu);

    epilogue_kernel<<<B_SZ, 256, 0, stream>>>(f, y, eps, vx, vmu, out, partials);
    reduce_kernel<<<1, 256, 0, stream>>>(partials, out);
}